// Round 14
// baseline (45.141 us; speedup 1.0000x reference)
//
#include <hip/hip_runtime.h>

#define BS 256

__device__ __forceinline__ float fast_acos(float x) {
    // Abramowitz & Stegun 4.4.45, branchless; |err| <= ~6.8e-5 rad.
    float ax = fabsf(x);
    float s  = sqrtf(fmaxf(0.f, 1.f - ax));
    float p  = fmaf(ax, fmaf(ax, fmaf(ax, -0.0187293f, 0.0742610f), -0.2121144f), 1.5707288f);
    float r  = s * p;
    return (x >= 0.f) ? r : 3.14159265358979f - r;
}

__device__ __forceinline__ float dir_item(float4 L, float4 O, float4 Tn, bool first) {
    // pred_c = conv_bbox(last + outputs[t])
    float pa = L.x + O.x, pb = L.y + O.y, pc = L.z + O.z, pd = L.w + O.w;
    float Px0 = pa - 0.5f * pc, Py0 = pb - 0.5f * pd, Px1 = pa, Py1 = pb;
    // true_c = conv_bbox(targets[t+1])
    float Tx0 = Tn.x - 0.5f * Tn.z, Ty0 = Tn.y - 0.5f * Tn.w, Tx1 = Tn.x, Ty1 = Tn.y;
    // last_eff: frame 0 -> conv once; frames >=1 -> conv twice (collapsed)
    float Lx1 = L.x - 0.5f * L.z, Ly1 = L.y - 0.5f * L.w;      // conv once
    float Lx0, Ly0;
    if (first) { Lx0 = Lx1; Ly0 = Ly1; Lx1 = L.x; Ly1 = L.y; }
    else       { Lx0 = 0.5f * (L.x - L.z); Ly0 = 0.5f * (L.y - L.w); }

    float lxs[5] = {0.5f * (Lx0 + Lx1), Lx0, Lx0, Lx1, Lx1};
    float lys[5] = {0.5f * (Ly0 + Ly1), Ly0, Ly1, Ly0, Ly1};
    float pxs[5] = {0.5f * (Px0 + Px1), Px0, Px0, Px1, Px1};
    float pys[5] = {0.5f * (Py0 + Py1), Py0, Py1, Py0, Py1};
    float txs[5] = {0.5f * (Tx0 + Tx1), Tx0, Tx0, Tx1, Tx1};
    float tys[5] = {0.5f * (Ty0 + Ty1), Ty0, Ty1, Ty0, Ty1};

    float acc = 0.f;
    #pragma unroll
    for (int k = 0; k < 5; ++k) {
        float pdx = pxs[k] - lxs[k], pdy = pys[k] - lys[k];
        float tdx = txs[k] - lxs[k], tdy = tys[k] - lys[k];
        float p2  = pdx * pdx + pdy * pdy;
        float t2  = tdx * tdx + tdy * tdy;
        float dot = pdx * tdx + pdy * tdy;
        float inv = rsqrtf(p2 * t2);   // ref's +1e-6 eps shifts cos by <=1e-5: within budget
        float cosang = fminf(1.0f, fmaxf(-1.0f, dot * inv));
        acc += fast_acos(cosang);
    }
    return acc;
}

__device__ __forceinline__ float sl1_4(float4 O, float4 D) {
    float s = 0.f;
    { float d = O.x - D.x, ad = fabsf(d); s += (ad < 1.f) ? 0.5f * d * d : ad - 0.5f; }
    { float d = O.y - D.y, ad = fabsf(d); s += (ad < 1.f) ? 0.5f * d * d : ad - 0.5f; }
    { float d = O.z - D.z, ad = fabsf(d); s += (ad < 1.f) ? 0.5f * d * d : ad - 0.5f; }
    { float d = O.w - D.w, ad = fabsf(d); s += (ad < 1.f) ? 0.5f * d * d : ad - 0.5f; }
    return s;
}

#define LD4(ptr) (*reinterpret_cast<const float4*>(ptr))

// One thread owns one p for 4 frames (grp g: t = 4g..4g+3). All 13 loads are
// issued up front and PINNED LIVE at one point via inline asm, with
// amdgpu_waves_per_eu(4,4) giving the allocator a ~128-VGPR budget -> 13-deep
// MLP per wave (previous rounds' loads were silently re-serialized at 32 VGPR).
__global__ __launch_bounds__(BS, 4) __attribute__((amdgpu_waves_per_eu(4, 4)))
void fused_kernel(const float* __restrict__ outputs,
                  const float* __restrict__ targets,
                  float* __restrict__ out,
                  float* __restrict__ partials,
                  int P, float w) {
    __shared__ float smem[BS / 64];
    long long gid = (long long)blockIdx.x * BS + threadIdx.x;
    float acc = 0.f;
    if (gid < 4ll * P) {
        int grp     = (int)(gid / P);          // 0..3
        long long p = gid - (long long)grp * P;
        const long long ts8 = 8ll * P, os4 = 4ll * P;
        const float* tb = targets + ((long long)(grp * 4) * P + p) * 8;
        const float* ob = outputs + ((long long)(grp * 4) * P + p) * 4;
        float*       wb = out + (long long)(grp * 4) * P + p;
        const bool has4 = (grp < 3);           // wave-uniform except 3 straddle blocks

        // ---- 13 independent loads, all issued up front ----
        float4 Tf0 = LD4(tb);
        float4 Tf1 = LD4(tb + ts8);
        float4 Tf2 = LD4(tb + 2 * ts8);
        float4 Tf3 = LD4(tb + 3 * ts8);
        float4 Ts0 = LD4(tb + 4);
        float4 Ts1 = LD4(tb + ts8 + 4);
        float4 Ts2 = LD4(tb + 2 * ts8 + 4);
        float4 Ts3 = LD4(tb + 3 * ts8 + 4);
        float4 O0  = LD4(ob);
        float4 O1  = LD4(ob + os4);
        float4 O2  = LD4(ob + 2 * os4);
        float4 O3  = LD4(ob + 3 * os4);
        float4 Tf4 = has4 ? LD4(tb + 4 * ts8) : make_float4(0.f, 0.f, 0.f, 0.f);

        // Pin all 13 loads live at one point: forces the scheduler to issue
        // them back-to-back (one s_waitcnt), instead of sinking to uses.
        asm volatile("" ::
            "v"(Tf0.x), "v"(Tf1.x), "v"(Tf2.x), "v"(Tf3.x), "v"(Tf4.x),
            "v"(Ts0.x), "v"(Ts1.x), "v"(Ts2.x), "v"(Ts3.x),
            "v"(O0.x),  "v"(O1.x),  "v"(O2.x),  "v"(O3.x));

        // ---- smooth-L1 for the 4 frames (finalize adds the dir constant) ----
        wb[0]       = sl1_4(O0, Ts0) * w;
        wb[P]       = sl1_4(O1, Ts1) * w;
        wb[2ll * P] = sl1_4(O2, Ts2) * w;
        wb[3ll * P] = sl1_4(O3, Ts3) * w;

        // ---- direction terms t = 4g .. 4g+2 (+3 if next row exists) ----
        acc  = dir_item(Tf0, O0, Tf1, grp == 0);
        acc += dir_item(Tf1, O1, Tf2, false);
        acc += dir_item(Tf2, O2, Tf3, false);
        if (has4) acc += dir_item(Tf3, O3, Tf4, false);
    }
    #pragma unroll
    for (int off = 32; off > 0; off >>= 1) acc += __shfl_down(acc, off, 64);
    int lane = threadIdx.x & 63, w64 = threadIdx.x >> 6;
    if (lane == 0) smem[w64] = acc;
    __syncthreads();
    if (threadIdx.x == 0) {
        float r = 0.f;
        #pragma unroll
        for (int i = 0; i < BS / 64; ++i) r += smem[i];
        partials[blockIdx.x] = r;
    }
}

__global__ void finalize_kernel(const float* __restrict__ partials, int nb,
                                float* __restrict__ out, long long n4, int P) {
    __shared__ double dsm[BS / 64];
    __shared__ float c_sh;
    double dacc = 0.0;
    for (int i = threadIdx.x; i < nb; i += BS) dacc += (double)partials[i];
    #pragma unroll
    for (int off = 32; off > 0; off >>= 1) dacc += __shfl_down(dacc, off, 64);
    int lane = threadIdx.x & 63, w = threadIdx.x >> 6;
    if (lane == 0) dsm[w] = dacc;
    __syncthreads();
    if (threadIdx.x == 0) {
        double tot = dsm[0] + dsm[1] + dsm[2] + dsm[3];
        c_sh = (float)(0.01 * 0.2 * tot / ((double)P * 15.0));
    }
    __syncthreads();
    float c = c_sh;

    float4* o4 = reinterpret_cast<float4*>(out);
    long long stride = (long long)gridDim.x * blockDim.x;
    for (long long i = (long long)blockIdx.x * blockDim.x + threadIdx.x; i < n4; i += stride) {
        float4 v = o4[i];
        v.x += c; v.y += c; v.z += c; v.w += c;
        o4[i] = v;
    }
}

extern "C" void kernel_launch(void* const* d_in, const int* in_sizes, int n_in,
                              void* d_out, int out_size, void* d_ws, size_t ws_size,
                              hipStream_t stream) {
    const float* outputs = (const float*)d_in[0];
    const float* targets = (const float*)d_in[1];
    float* out = (float*)d_out;
    float* partials = (float*)d_ws;

    const int T = 16;
    int P = in_sizes[0] / (T * 4);                 // 200000

    long long nthreads = 4ll * P;                  // one per (p, t-quarter)
    int nb1 = (int)((nthreads + BS - 1) / BS);     // 3125 blocks
    fused_kernel<<<nb1, BS, 0, stream>>>(outputs, targets, out, partials,
                                         P, 0.99f / (float)P);

    long long n4 = (long long)out_size / 4;        // out_size = 16P, divisible by 4
    int nb2 = (int)((n4 + BS - 1) / BS);
    if (nb2 > 2048) nb2 = 2048;
    finalize_kernel<<<nb2, BS, 0, stream>>>(partials, nb1, out, n4, P);
}

// Round 15
// 44.233 us; speedup vs baseline: 1.0205x; 1.0205x over previous
//
#include <hip/hip_runtime.h>

#define BS 256

typedef float f32x4 __attribute__((ext_vector_type(4)));

__device__ __forceinline__ float fast_acos(float x) {
    // Abramowitz & Stegun 4.4.45, branchless; |err| <= ~6.8e-5 rad.
    float ax = fabsf(x);
    float s  = sqrtf(fmaxf(0.f, 1.f - ax));
    float p  = fmaf(ax, fmaf(ax, fmaf(ax, -0.0187293f, 0.0742610f), -0.2121144f), 1.5707288f);
    float r  = s * p;
    return (x >= 0.f) ? r : 3.14159265358979f - r;
}

__device__ __forceinline__ float dir_item(f32x4 L, f32x4 O, f32x4 Tn, bool first) {
    // pred_c = conv_bbox(last + outputs[t])
    float pa = L.x + O.x, pb = L.y + O.y, pc = L.z + O.z, pd = L.w + O.w;
    float Px0 = pa - 0.5f * pc, Py0 = pb - 0.5f * pd, Px1 = pa, Py1 = pb;
    // true_c = conv_bbox(targets[t+1])
    float Tx0 = Tn.x - 0.5f * Tn.z, Ty0 = Tn.y - 0.5f * Tn.w, Tx1 = Tn.x, Ty1 = Tn.y;
    // last_eff: frame 0 -> conv once; frames >=1 -> conv twice (collapsed)
    float Lx1 = L.x - 0.5f * L.z, Ly1 = L.y - 0.5f * L.w;      // conv once
    float Lx0, Ly0;
    if (first) { Lx0 = Lx1; Ly0 = Ly1; Lx1 = L.x; Ly1 = L.y; }
    else       { Lx0 = 0.5f * (L.x - L.z); Ly0 = 0.5f * (L.y - L.w); }

    float lxs[5] = {0.5f * (Lx0 + Lx1), Lx0, Lx0, Lx1, Lx1};
    float lys[5] = {0.5f * (Ly0 + Ly1), Ly0, Ly1, Ly0, Ly1};
    float pxs[5] = {0.5f * (Px0 + Px1), Px0, Px0, Px1, Px1};
    float pys[5] = {0.5f * (Py0 + Py1), Py0, Py1, Py0, Py1};
    float txs[5] = {0.5f * (Tx0 + Tx1), Tx0, Tx0, Tx1, Tx1};
    float tys[5] = {0.5f * (Ty0 + Ty1), Ty0, Ty1, Ty0, Ty1};

    float acc = 0.f;
    #pragma unroll
    for (int k = 0; k < 5; ++k) {
        float pdx = pxs[k] - lxs[k], pdy = pys[k] - lys[k];
        float tdx = txs[k] - lxs[k], tdy = tys[k] - lys[k];
        float p2  = pdx * pdx + pdy * pdy;
        float t2  = tdx * tdx + tdy * tdy;
        float dot = pdx * tdx + pdy * tdy;
        float inv = rsqrtf(p2 * t2);   // ref's +1e-6 eps shifts cos by <=1e-5: within budget
        float cosang = fminf(1.0f, fmaxf(-1.0f, dot * inv));
        acc += fast_acos(cosang);
    }
    return acc;
}

__device__ __forceinline__ float sl1_4(f32x4 O, f32x4 D) {
    float s = 0.f;
    { float d = O.x - D.x, ad = fabsf(d); s += (ad < 1.f) ? 0.5f * d * d : ad - 0.5f; }
    { float d = O.y - D.y, ad = fabsf(d); s += (ad < 1.f) ? 0.5f * d * d : ad - 0.5f; }
    { float d = O.z - D.z, ad = fabsf(d); s += (ad < 1.f) ? 0.5f * d * d : ad - 0.5f; }
    { float d = O.w - D.w, ad = fabsf(d); s += (ad < 1.f) ? 0.5f * d * d : ad - 0.5f; }
    return s;
}

// One thread owns one p for 4 frames (grp g: t = 4g..4g+3). The 13 tile loads
// are a SINGLE inline-asm block: 13 global_load_dwordx4 issued back-to-back +
// one s_waitcnt vmcnt(0). The compiler cannot split/sink/reload these, so the
// wave genuinely has 13 loads in flight (prior rounds: allocator kept VGPR=32
// and re-serialized every load).
__global__ __launch_bounds__(BS, 4)
void fused_kernel(const float* __restrict__ outputs,
                  const float* __restrict__ targets,
                  float* __restrict__ out,
                  float* __restrict__ partials,
                  int P, float w) {
    __shared__ float smem[BS / 64];
    long long gid = (long long)blockIdx.x * BS + threadIdx.x;
    float acc = 0.f;
    if (gid < 4ll * P) {
        int grp     = (int)(gid / P);          // 0..3
        long long p = gid - (long long)grp * P;
        const long long ts8 = 8ll * P, os4 = 4ll * P;
        const float* tb = targets + ((long long)(grp * 4) * P + p) * 8;
        const float* ob = outputs + ((long long)(grp * 4) * P + p) * 4;
        float*       wb = out + (long long)(grp * 4) * P + p;
        const bool has4 = (grp < 3);

        const float* aTf0 = tb;
        const float* aTf1 = tb + ts8;
        const float* aTf2 = tb + 2 * ts8;
        const float* aTf3 = tb + 3 * ts8;
        const float* aTf4 = has4 ? tb + 4 * ts8 : tb;   // clamp: grp 3 value unused
        const float* aTs0 = tb + 4;
        const float* aTs1 = tb + ts8 + 4;
        const float* aTs2 = tb + 2 * ts8 + 4;
        const float* aTs3 = tb + 3 * ts8 + 4;
        const float* aO0  = ob;
        const float* aO1  = ob + os4;
        const float* aO2  = ob + 2 * os4;
        const float* aO3  = ob + 3 * os4;

        f32x4 Tf0, Tf1, Tf2, Tf3, Tf4, Ts0, Ts1, Ts2, Ts3, O0, O1, O2, O3;
        asm volatile(
            "global_load_dwordx4 %0, %13, off\n\t"
            "global_load_dwordx4 %1, %14, off\n\t"
            "global_load_dwordx4 %2, %15, off\n\t"
            "global_load_dwordx4 %3, %16, off\n\t"
            "global_load_dwordx4 %4, %17, off\n\t"
            "global_load_dwordx4 %5, %18, off\n\t"
            "global_load_dwordx4 %6, %19, off\n\t"
            "global_load_dwordx4 %7, %20, off\n\t"
            "global_load_dwordx4 %8, %21, off\n\t"
            "global_load_dwordx4 %9, %22, off\n\t"
            "global_load_dwordx4 %10, %23, off\n\t"
            "global_load_dwordx4 %11, %24, off\n\t"
            "global_load_dwordx4 %12, %25, off\n\t"
            "s_waitcnt vmcnt(0)"
            : "=&v"(Tf0), "=&v"(Tf1), "=&v"(Tf2), "=&v"(Tf3), "=&v"(Tf4),
              "=&v"(Ts0), "=&v"(Ts1), "=&v"(Ts2), "=&v"(Ts3),
              "=&v"(O0),  "=&v"(O1),  "=&v"(O2),  "=&v"(O3)
            : "v"(aTf0), "v"(aTf1), "v"(aTf2), "v"(aTf3), "v"(aTf4),
              "v"(aTs0), "v"(aTs1), "v"(aTs2), "v"(aTs3),
              "v"(aO0),  "v"(aO1),  "v"(aO2),  "v"(aO3)
            : "memory");

        // ---- smooth-L1 for the 4 frames (finalize adds the dir constant) ----
        wb[0]       = sl1_4(O0, Ts0) * w;
        wb[P]       = sl1_4(O1, Ts1) * w;
        wb[2ll * P] = sl1_4(O2, Ts2) * w;
        wb[3ll * P] = sl1_4(O3, Ts3) * w;

        // ---- direction terms t = 4g .. 4g+2 (+3 if next row exists) ----
        acc  = dir_item(Tf0, O0, Tf1, grp == 0);
        acc += dir_item(Tf1, O1, Tf2, false);
        acc += dir_item(Tf2, O2, Tf3, false);
        if (has4) acc += dir_item(Tf3, O3, Tf4, false);
    }
    #pragma unroll
    for (int off = 32; off > 0; off >>= 1) acc += __shfl_down(acc, off, 64);
    int lane = threadIdx.x & 63, w64 = threadIdx.x >> 6;
    if (lane == 0) smem[w64] = acc;
    __syncthreads();
    if (threadIdx.x == 0) {
        float r = 0.f;
        #pragma unroll
        for (int i = 0; i < BS / 64; ++i) r += smem[i];
        partials[blockIdx.x] = r;
    }
}

__global__ void finalize_kernel(const float* __restrict__ partials, int nb,
                                float* __restrict__ out, long long n4, int P) {
    __shared__ double dsm[BS / 64];
    __shared__ float c_sh;
    double dacc = 0.0;
    for (int i = threadIdx.x; i < nb; i += BS) dacc += (double)partials[i];
    #pragma unroll
    for (int off = 32; off > 0; off >>= 1) dacc += __shfl_down(dacc, off, 64);
    int lane = threadIdx.x & 63, w = threadIdx.x >> 6;
    if (lane == 0) dsm[w] = dacc;
    __syncthreads();
    if (threadIdx.x == 0) {
        double tot = dsm[0] + dsm[1] + dsm[2] + dsm[3];
        c_sh = (float)(0.01 * 0.2 * tot / ((double)P * 15.0));
    }
    __syncthreads();
    float c = c_sh;

    float4* o4 = reinterpret_cast<float4*>(out);
    long long stride = (long long)gridDim.x * blockDim.x;
    for (long long i = (long long)blockIdx.x * blockDim.x + threadIdx.x; i < n4; i += stride) {
        float4 v = o4[i];
        v.x += c; v.y += c; v.z += c; v.w += c;
        o4[i] = v;
    }
}

extern "C" void kernel_launch(void* const* d_in, const int* in_sizes, int n_in,
                              void* d_out, int out_size, void* d_ws, size_t ws_size,
                              hipStream_t stream) {
    const float* outputs = (const float*)d_in[0];
    const float* targets = (const float*)d_in[1];
    float* out = (float*)d_out;
    float* partials = (float*)d_ws;

    const int T = 16;
    int P = in_sizes[0] / (T * 4);                 // 200000

    long long nthreads = 4ll * P;                  // one per (p, t-quarter)
    int nb1 = (int)((nthreads + BS - 1) / BS);     // 3125 blocks
    fused_kernel<<<nb1, BS, 0, stream>>>(outputs, targets, out, partials,
                                         P, 0.99f / (float)P);

    long long n4 = (long long)out_size / 4;        // out_size = 16P, divisible by 4
    int nb2 = (int)((n4 + BS - 1) / BS);
    if (nb2 > 2048) nb2 = 2048;
    finalize_kernel<<<nb2, BS, 0, stream>>>(partials, nb1, out, n4, P);
}